// Round 12
// baseline (52.170 us; speedup 1.0000x reference)
//
#include <hip/hip_runtime.h>

// Encoder is dead; LSTM input is constant zero => batch dim uniform. Real
// work: one 512-wide LSTM, 16 serial steps, broadcast 16x4 scalars to
// (16,1024,4). R11 skeleton (proven 31.4us): 32 workers at blockIdx%8==0,
// lane-owns-slot tagged exchange (tag<<32|float), sequential sc0->LLC poll,
// sc0+agent publish, one barrier/step, h1-local prologue, hw exp2/rcp.
// This revision: PADDED SLOT ARRAYS. 8B-packed slots put 16 slots on one
// 128B LLC line -> 512 concurrent pollers per line (16 slots x 32 blocks);
// producer stores queue behind them. Stride slots by 128B (one line per
// slot) when ws_size permits, 32B/16B/out-tail degradation otherwise.
// Protocol, arithmetic, and schedule are bit-identical to R11.

#define NTHR   512
#define HID    512
#define TSTEPS 16
#define KPB    16      // k's per worker block
#define OUTB   16      // ranks that write output rows
#define NWORK  32

typedef unsigned long long ull;

#define LOG2E  1.44269504f

__device__ __forceinline__ float fexp2(float x) { return __builtin_amdgcn_exp2f(x); }
__device__ __forceinline__ float frcp(float x)  { return __builtin_amdgcn_rcpf(x); }
// sigm(x)=1/(1+e^-x): x->-inf => rcp(inf)=0; x->+inf => 1. Correct saturation.
__device__ __forceinline__ float sigm(float x)  { return frcp(1.0f + fexp2(-LOG2E * x)); }
// tanh(x)=1-2/(e^{2x}+1): x->+inf => 1; x->-inf => -1. Correct saturation.
__device__ __forceinline__ float tanh_f(float x) {
  const float e = fexp2(2.0f * LOG2E * x);
  return 1.0f - 2.0f * frcp(e + 1.0f);
}

// Single sc0 probe: L1-bypass, serviced from this XCD's L2 (fast when the
// line is local; correctness never depends on it).
__device__ __forceinline__ ull probe_l2(const ull* p) {
  ull v;
  asm volatile("global_load_dwordx2 %0, %1, off sc0\n\ts_waitcnt vmcnt(0)"
               : "=v"(v) : "v"(p) : "memory");
  return v;
}

// Sequential dual poll: one sc0 probe, then one agent/LLC probe.
__device__ __forceinline__ float poll_h(const ull* sL2, const ull* sLLC,
                                        size_t off, unsigned tag, bool fast) {
  ull v;
  if (fast) {
    for (;;) {
      v = probe_l2(sL2 + off);                 // fast leg
      if ((unsigned)(v >> 32) == tag) break;
      v = __hip_atomic_load(sLLC + off, __ATOMIC_RELAXED,
                            __HIP_MEMORY_SCOPE_AGENT);   // correctness leg
      if ((unsigned)(v >> 32) == tag) break;
    }
  } else {
    do {
      v = __hip_atomic_load(sLLC + off, __ATOMIC_RELAXED,
                            __HIP_MEMORY_SCOPE_AGENT);
    } while ((unsigned)(v >> 32) != tag);
  }
  return __uint_as_float((unsigned)v);
}

__device__ __forceinline__ void publish(ull* sL2, ull* sLLC, size_t off, ull pk,
                                        bool fast) {
  if (fast) {
    asm volatile("global_store_dwordx2 %0, %1, off sc0"
                 :: "v"(sL2 + off), "v"(pk) : "memory");
  }
  __hip_atomic_store(sLLC + off, pk, __ATOMIC_RELAXED, __HIP_MEMORY_SCOPE_AGENT);
}

__global__ __launch_bounds__(NTHR, 2) void lstm_seq_kernel(
    const float* __restrict__ Whh,
    const float* __restrict__ bih,
    const float* __restrict__ bhh,
    const float* __restrict__ Wo,
    const float* __restrict__ bo,
    float* __restrict__ out,
    ull* sLLC,              // [2*512 << sh] device-coherent tagged slots
    ull* sL2,               // [2*512 << sh] XCD-L2 tagged slots (sc0 ops)
    int sh,                 // slot stride = (8 << sh) bytes (anti-contention)
    int mode)               // 1 = colocated roster + L2 fast leg, 0 = LLC only
{
  // ---- roster: mode 1 -> workers are blockIdx%8==0 (one XCD heuristic) ----
  int r;
  if (mode) {
    if (blockIdx.x & 7) return;       // non-worker: pure dispatch cost
    r = (int)(blockIdx.x >> 3);
  } else {
    r = (int)blockIdx.x;
  }
  if (r >= NWORK) return;
  const bool fast = (mode != 0);

  const int tid = threadIdx.x;
  const int w  = tid >> 6;           // wave id = h column chunk (64 cols)
  const int l  = tid & 63;           // lane = block-local gate-row
  const int g  = l >> 4;             // gate (torch order i,f,g,o)
  const int kk = l & 15;             // k within block
  const int grow = g * HID + r * KPB + kk;

  __shared__ __align__(16) float chbuf[8][64];  // per-wave h chunk (exclusive)
  __shared__ float gpT[2][8][64];    // partials, parity-double-buffered
  __shared__ float hstash[HID];      // h_{r+1} for this block's output row
  __shared__ float vals[4];

  // ---- weights: one 64-col slice of one gate-row per lane (64 VGPRs),
  // overlapped with the bias/h1 prologue (no sync until the s=2 matvec) ----
  float4 wreg[16];
  {
    const float4* Wr = reinterpret_cast<const float4*>(
        Whh + (size_t)grow * HID + w * 64);
#pragma unroll
    for (int j = 0; j < 16; ++j) wreg[j] = Wr[j];
  }

  // ---- h1 = f(bias) locally for THIS thread's h column (k = tid):
  // h0 == 0 kills the recurrent term, so steps 1-2 need no exchange in.
  {
    const float gi = bih[tid]           + bhh[tid];
    const float gf = bih[HID + tid]     + bhh[HID + tid];
    const float gg = bih[2*HID + tid]   + bhh[2*HID + tid];
    const float go = bih[3*HID + tid]   + bhh[3*HID + tid];
    const float c1 = sigm(gf) * 0.0f + sigm(gi) * tanh_f(gg);
    const float h1 = sigm(go) * tanh_f(c1);
    chbuf[w][l] = h1;                // wave-private: no barrier needed
    if (r == 0) hstash[tid] = h1;    // out row 0 uses h1
  }

  // ---- reducer lanes: bias sums + c1 for owned k = r*16+tid ----
  float c_state = 0.0f;
  float bs_i = 0.f, bs_f = 0.f, bs_g = 0.f, bs_o = 0.f;
  if (tid < KPB) {
    const int k = r * KPB + tid;
    bs_i = bih[k]           + bhh[k];
    bs_f = bih[HID + k]     + bhh[HID + k];
    bs_g = bih[2*HID + k]   + bhh[2*HID + k];
    bs_o = bih[3*HID + k]   + bhh[3*HID + k];
    c_state = sigm(bs_f) * 0.0f + sigm(bs_i) * tanh_f(bs_g);
  }

  // ---- steps 2..16: matvec(h_{s-1}) -> reduce -> publish h_s -> stage ----
  for (int s = 2; s <= TSTEPS; ++s) {
    const int p = s & 1;

    float4 a = make_float4(0.f, 0.f, 0.f, 0.f);
    {
      const float4* hq = reinterpret_cast<const float4*>(&chbuf[w][0]);
#pragma unroll
      for (int j = 0; j < 16; ++j) {
        const float4 h4 = hq[j];   // broadcast read: conflict-free
        a.x = fmaf(wreg[j].x, h4.x, a.x);
        a.y = fmaf(wreg[j].y, h4.y, a.y);
        a.z = fmaf(wreg[j].z, h4.z, a.z);
        a.w = fmaf(wreg[j].w, h4.w, a.w);
      }
    }
    gpT[p][w][l] = (a.x + a.y) + (a.z + a.w);
    __syncthreads();   // the only barrier per step

    // reducer lane k: sum 8 chunk-partials per gate, pointwise, publish.
    // Next step's partials go to gpT[p^1] -> no WAR with these reads.
    if (tid < KPB) {
      float p0 = 0.f, p1 = 0.f, p2 = 0.f, p3 = 0.f;
#pragma unroll
      for (int j = 0; j < 8; ++j) {
        p0 += gpT[p][j][tid];
        p1 += gpT[p][j][16 + tid];
        p2 += gpT[p][j][32 + tid];
        p3 += gpT[p][j][48 + tid];
      }
      const float gi = p0 + bs_i, gf = p1 + bs_f;
      const float gg = p2 + bs_g, go = p3 + bs_o;
      c_state = sigm(gf) * c_state + sigm(gi) * tanh_f(gg);
      const float hv = sigm(go) * tanh_f(c_state);
      const ull pk = ((ull)(unsigned)s << 32) | (ull)__float_as_uint(hv);
      publish(sL2, sLLC, (size_t)(p * HID + r * KPB + tid) << sh, pk, fast);
    }

    // stage h_s for the next matvec (s<16); capture hstash = h_{r+1} at s==r+1
    if (s < TSTEPS) {
      const float h = poll_h(sL2, sLLC, (size_t)(p * HID + w * 64 + l) << sh,
                             (unsigned)s, fast);
      if (r >= 1 && r < OUTB - 1 && s == r + 1) hstash[w * 64 + l] = h;
      chbuf[w][l] = h;   // wave-private; matvec reads of prior value are done
    }
  }

  if (r >= OUTB) return;   // ranks 16..31 only feed the recurrence

  if (r == OUTB - 1) {     // h_16 (tag 16, parity 0) never staged in-loop
    hstash[w * 64 + l] = poll_h(sL2, sLLC, (size_t)(w * 64 + l) << sh,
                                (unsigned)TSTEPS, fast);
  }
  __syncthreads();

  // ---- output row t = r: 4 dot products of length 512, then broadcast ----
  if (tid < 256) {
    const int wo = tid >> 6;  // output dim 0..3 (one wave each)
    const int ll = tid & 63;
    float sacc = 0.0f;
#pragma unroll
    for (int j = 0; j < 8; ++j) {
      const int k2 = ll + 64 * j;
      sacc = fmaf(Wo[wo * HID + k2], hstash[k2], sacc);
    }
#pragma unroll
    for (int m = 32; m > 0; m >>= 1) sacc += __shfl_xor(sacc, m);
    if (ll == 0) vals[wo] = sacc + bo[wo];
  }
  __syncthreads();

  const float4 vv = make_float4(vals[0], vals[1], vals[2], vals[3]);
  float4* out4 = reinterpret_cast<float4*>(out) + (size_t)r * 1024;
  out4[tid]       = vv;   // row t=r : 1024 batch rows x 4 floats
  out4[tid + 512] = vv;
}

extern "C" void kernel_launch(void* const* d_in, const int* in_sizes, int n_in,
                              void* d_out, int out_size, void* d_ws, size_t ws_size,
                              hipStream_t stream) {
  // setup_inputs() order:
  // 0 images, 1 W1, 2 b1, 3 W2, 4 b2, 5 W3, 6 b3, 7 We, 8 be,
  // 9 Wih, 10 Whh, 11 bih, 12 bhh, 13 Wg, 14 bg, 15 Wk, 16 bk,
  // 17 Wo, 18 bo, 19 Wc, 20 bc
  const float* Whh = (const float*)d_in[10];
  const float* bih = (const float*)d_in[11];
  const float* bhh = (const float*)d_in[12];
  const float* Wo  = (const float*)d_in[17];
  const float* bo  = (const float*)d_in[18];
  float* out = (float*)d_out;

  // Slot arrays: 2 parities x 512 slots, stride (8<<sh) bytes, two arrays
  // (LLC + sc0). No reset needed: tagged values are replay-invariant, and
  // 0xAA poison never matches tags 2..16.
  // sh=4 -> 128B/slot (1 LLC line per slot, 256KB total): kills the
  // 512-pollers-per-line contention. Degrade 32B -> 16B -> out-tail.
  ull* sLLC; ull* sL2; int sh; int mode; int grid;
  size_t need4 = (size_t)2 * (2 * HID * 8) << 4;   // 256 KB
  size_t need2 = (size_t)2 * (2 * HID * 8) << 2;   // 64 KB
  size_t need0 = (size_t)2 * (2 * HID * 8);        // 16 KB
  if (d_ws != nullptr && ws_size >= need4) {
    sh = 4;
  } else if (d_ws != nullptr && ws_size >= need2) {
    sh = 2;
  } else if (d_ws != nullptr && ws_size >= need0) {
    sh = 0;
  } else {
    sh = -1;
  }
  if (sh >= 0) {
    sLLC = (ull*)d_ws;
    sL2  = sLLC + ((size_t)(2 * HID) << sh);
    mode = 1;
    grid = NWORK * 8;   // workers = blockIdx%8==0 -> one XCD (speed heuristic)
  } else {
    // Out-tail fallback: LLC-only, packed (no sc0 dirty lines over out).
    // Rank-15 reads all slots strictly before overwriting this region.
    sLLC = (ull*)(out + (size_t)out_size) - 2 * HID;
    sL2  = sLLC;
    sh   = 0;
    mode = 0;
    grid = NWORK;
  }

  lstm_seq_kernel<<<dim3(grid), dim3(NTHR), 0, stream>>>(
      Whh, bih, bhh, Wo, bo, out, sLLC, sL2, sh, mode);
}

// Round 13
// 29.476 us; speedup vs baseline: 1.7699x; 1.7699x over previous
//
#include <hip/hip_runtime.h>

// Encoder is dead; LSTM input is constant zero => batch dim uniform. Real
// work: one 512-wide LSTM, 16 serial steps, broadcast 16x4 scalars to
// (16,1024,4). R11 skeleton (proven 31.4us best): 32 workers at
// blockIdx%8==0, lane-owns-slot PACKED tagged exchange (tag<<32|float),
// sequential sc0->LLC poll, sc0+agent publish, one barrier/step, h1-local
// prologue, hw exp2/rcp activations.
// This revision: COALESCED WEIGHT STAGING. R11 loaded weights with lane->row
// mapping (2KB stride): 64 lines touched per instruction, latency-bound
// ~5us. Now: the block's 64 gate-rows are 4 contiguous 32KB regions ->
// float4-coalesced global loads into padded LDS (row stride 516 floats,
// 16B-aligned), one barrier, then LDS->wreg (8-way conflict, one-time).
// wreg values are bit-identical to R11; everything else unchanged.

#define NTHR   512
#define HID    512
#define TSTEPS 16
#define KPB    16      // k's per worker block
#define OUTB   16      // ranks that write output rows
#define NWORK  32
#define SW     516     // LDS weight row stride in floats (2064B: 16B-aligned)

typedef unsigned long long ull;

#define LOG2E  1.44269504f

__device__ __forceinline__ float fexp2(float x) { return __builtin_amdgcn_exp2f(x); }
__device__ __forceinline__ float frcp(float x)  { return __builtin_amdgcn_rcpf(x); }
// sigm(x)=1/(1+e^-x): x->-inf => rcp(inf)=0; x->+inf => 1. Correct saturation.
__device__ __forceinline__ float sigm(float x)  { return frcp(1.0f + fexp2(-LOG2E * x)); }
// tanh(x)=1-2/(e^{2x}+1): x->+inf => 1; x->-inf => -1. Correct saturation.
__device__ __forceinline__ float tanh_f(float x) {
  const float e = fexp2(2.0f * LOG2E * x);
  return 1.0f - 2.0f * frcp(e + 1.0f);
}

// Single sc0 probe: L1-bypass, serviced from this XCD's L2 (fast when the
// line is local; correctness never depends on it).
__device__ __forceinline__ ull probe_l2(const ull* p) {
  ull v;
  asm volatile("global_load_dwordx2 %0, %1, off sc0\n\ts_waitcnt vmcnt(0)"
               : "=v"(v) : "v"(p) : "memory");
  return v;
}

// Sequential dual poll: one sc0 probe, then one agent/LLC probe.
__device__ __forceinline__ float poll_h(const ull* sL2, const ull* sLLC,
                                        int idx, unsigned tag, bool fast) {
  ull v;
  if (fast) {
    for (;;) {
      v = probe_l2(sL2 + idx);                 // fast leg
      if ((unsigned)(v >> 32) == tag) break;
      v = __hip_atomic_load(sLLC + idx, __ATOMIC_RELAXED,
                            __HIP_MEMORY_SCOPE_AGENT);   // correctness leg
      if ((unsigned)(v >> 32) == tag) break;
    }
  } else {
    do {
      v = __hip_atomic_load(sLLC + idx, __ATOMIC_RELAXED,
                            __HIP_MEMORY_SCOPE_AGENT);
    } while ((unsigned)(v >> 32) != tag);
  }
  return __uint_as_float((unsigned)v);
}

__device__ __forceinline__ void publish(ull* sL2, ull* sLLC, int idx, ull pk,
                                        bool fast) {
  if (fast) {
    asm volatile("global_store_dwordx2 %0, %1, off sc0"
                 :: "v"(sL2 + idx), "v"(pk) : "memory");
  }
  __hip_atomic_store(sLLC + idx, pk, __ATOMIC_RELAXED, __HIP_MEMORY_SCOPE_AGENT);
}

__global__ __launch_bounds__(NTHR, 2) void lstm_seq_kernel(
    const float* __restrict__ Whh,
    const float* __restrict__ bih,
    const float* __restrict__ bhh,
    const float* __restrict__ Wo,
    const float* __restrict__ bo,
    float* __restrict__ out,
    ull* sLLC,              // [2][512] device-coherent tagged slots (packed)
    ull* sL2,               // [2][512] XCD-L2 tagged slots (sc0 ops)
    int mode)               // 1 = colocated roster + L2 fast leg, 0 = LLC only
{
  // ---- roster: mode 1 -> workers are blockIdx%8==0 (one XCD heuristic) ----
  int r;
  if (mode) {
    if (blockIdx.x & 7) return;       // non-worker: pure dispatch cost
    r = (int)(blockIdx.x >> 3);
  } else {
    r = (int)blockIdx.x;
  }
  if (r >= NWORK) return;
  const bool fast = (mode != 0);

  const int tid = threadIdx.x;
  const int w  = tid >> 6;           // wave id = h column chunk (64 cols)
  const int l  = tid & 63;           // lane = block-local gate-row
  // block-local gate-row l: gate g = l>>4, unit kk = l&15; global row
  // grow = g*HID + r*KPB + kk. Note region-row (g*16+kk) == l exactly.

  __shared__ float ldsw[64 * SW];               // 132KB weight staging
  __shared__ __align__(16) float chbuf[8][64];  // per-wave h chunk (exclusive)
  __shared__ float gpT[2][8][64];    // partials, parity-double-buffered
  __shared__ float hstash[HID];      // h_{r+1} for this block's output row
  __shared__ float vals[4];

  // ---- phase 1: coalesced global -> LDS weight staging ----
  // Block's weights = 4 contiguous 32KB regions (16 rows x 512 cols each).
#pragma unroll
  for (int g4 = 0; g4 < 4; ++g4) {
    const float* base = Whh + ((size_t)g4 * HID + (size_t)r * KPB) * HID;
#pragma unroll
    for (int it = 0; it < 4; ++it) {
      const int flat = it * 2048 + tid * 4;     // float index in region
      const float4 v = *reinterpret_cast<const float4*>(base + flat);
      const int rw = flat >> 9;                 // row within region (0..15)
      const int cl = flat & 511;
      *reinterpret_cast<float4*>(&ldsw[(g4 * 16 + rw) * SW + cl]) = v;
    }
  }

  // ---- h1 = f(bias) locally for THIS thread's h column (k = tid):
  // h0 == 0 kills the recurrent term; overlaps the staging loads above.
  {
    const float gi = bih[tid]           + bhh[tid];
    const float gf = bih[HID + tid]     + bhh[HID + tid];
    const float gg = bih[2*HID + tid]   + bhh[2*HID + tid];
    const float go = bih[3*HID + tid]   + bhh[3*HID + tid];
    const float c1 = sigm(gf) * 0.0f + sigm(gi) * tanh_f(gg);
    const float h1 = sigm(go) * tanh_f(c1);
    chbuf[w][l] = h1;                // wave-private: no barrier needed
    if (r == 0) hstash[tid] = h1;    // out row 0 uses h1
  }

  // ---- reducer lanes: bias sums + c1 for owned k = r*16+tid ----
  float c_state = 0.0f;
  float bs_i = 0.f, bs_f = 0.f, bs_g = 0.f, bs_o = 0.f;
  if (tid < KPB) {
    const int k = r * KPB + tid;
    bs_i = bih[k]           + bhh[k];
    bs_f = bih[HID + k]     + bhh[HID + k];
    bs_g = bih[2*HID + k]   + bhh[2*HID + k];
    bs_o = bih[3*HID + k]   + bhh[3*HID + k];
    c_state = sigm(bs_f) * 0.0f + sigm(bs_i) * tanh_f(bs_g);
  }

  __syncthreads();   // staging complete

  // ---- phase 2: LDS -> registers (row l, cols [64w, 64w+64)) ----
  float4 wreg[16];
#pragma unroll
  for (int j = 0; j < 16; ++j)
    wreg[j] = *reinterpret_cast<const float4*>(&ldsw[l * SW + w * 64 + j * 4]);

  // ---- steps 2..16: matvec(h_{s-1}) -> reduce -> publish h_s -> stage ----
  for (int s = 2; s <= TSTEPS; ++s) {
    const int p = s & 1;

    float4 a = make_float4(0.f, 0.f, 0.f, 0.f);
    {
      const float4* hq = reinterpret_cast<const float4*>(&chbuf[w][0]);
#pragma unroll
      for (int j = 0; j < 16; ++j) {
        const float4 h4 = hq[j];   // broadcast read: conflict-free
        a.x = fmaf(wreg[j].x, h4.x, a.x);
        a.y = fmaf(wreg[j].y, h4.y, a.y);
        a.z = fmaf(wreg[j].z, h4.z, a.z);
        a.w = fmaf(wreg[j].w, h4.w, a.w);
      }
    }
    gpT[p][w][l] = (a.x + a.y) + (a.z + a.w);
    __syncthreads();   // the only barrier per step

    // reducer lane k: sum 8 chunk-partials per gate, pointwise, publish.
    // Next step's partials go to gpT[p^1] -> no WAR with these reads.
    if (tid < KPB) {
      float p0 = 0.f, p1 = 0.f, p2 = 0.f, p3 = 0.f;
#pragma unroll
      for (int j = 0; j < 8; ++j) {
        p0 += gpT[p][j][tid];
        p1 += gpT[p][j][16 + tid];
        p2 += gpT[p][j][32 + tid];
        p3 += gpT[p][j][48 + tid];
      }
      const float gi = p0 + bs_i, gf = p1 + bs_f;
      const float gg = p2 + bs_g, go = p3 + bs_o;
      c_state = sigm(gf) * c_state + sigm(gi) * tanh_f(gg);
      const float hv = sigm(go) * tanh_f(c_state);
      const ull pk = ((ull)(unsigned)s << 32) | (ull)__float_as_uint(hv);
      publish(sL2, sLLC, p * HID + r * KPB + tid, pk, fast);
    }

    // stage h_s for the next matvec (s<16); capture hstash = h_{r+1} at s==r+1
    if (s < TSTEPS) {
      const float h = poll_h(sL2, sLLC, p * HID + w * 64 + l, (unsigned)s, fast);
      if (r >= 1 && r < OUTB - 1 && s == r + 1) hstash[w * 64 + l] = h;
      chbuf[w][l] = h;   // wave-private; matvec reads of prior value are done
    }
  }

  if (r >= OUTB) return;   // ranks 16..31 only feed the recurrence

  if (r == OUTB - 1) {     // h_16 (tag 16, parity 0) never staged in-loop
    hstash[w * 64 + l] = poll_h(sL2, sLLC, w * 64 + l, (unsigned)TSTEPS, fast);
  }
  __syncthreads();

  // ---- output row t = r: 4 dot products of length 512, then broadcast ----
  if (tid < 256) {
    const int wo = tid >> 6;  // output dim 0..3 (one wave each)
    const int ll = tid & 63;
    float sacc = 0.0f;
#pragma unroll
    for (int j = 0; j < 8; ++j) {
      const int k2 = ll + 64 * j;
      sacc = fmaf(Wo[wo * HID + k2], hstash[k2], sacc);
    }
#pragma unroll
    for (int m = 32; m > 0; m >>= 1) sacc += __shfl_xor(sacc, m);
    if (ll == 0) vals[wo] = sacc + bo[wo];
  }
  __syncthreads();

  const float4 vv = make_float4(vals[0], vals[1], vals[2], vals[3]);
  float4* out4 = reinterpret_cast<float4*>(out) + (size_t)r * 1024;
  out4[tid]       = vv;   // row t=r : 1024 batch rows x 4 floats
  out4[tid + 512] = vv;
}

extern "C" void kernel_launch(void* const* d_in, const int* in_sizes, int n_in,
                              void* d_out, int out_size, void* d_ws, size_t ws_size,
                              hipStream_t stream) {
  // setup_inputs() order:
  // 0 images, 1 W1, 2 b1, 3 W2, 4 b2, 5 W3, 6 b3, 7 We, 8 be,
  // 9 Wih, 10 Whh, 11 bih, 12 bhh, 13 Wg, 14 bg, 15 Wk, 16 bk,
  // 17 Wo, 18 bo, 19 Wc, 20 bc
  const float* Whh = (const float*)d_in[10];
  const float* bih = (const float*)d_in[11];
  const float* bhh = (const float*)d_in[12];
  const float* Wo  = (const float*)d_in[17];
  const float* bo  = (const float*)d_in[18];
  float* out = (float*)d_out;

  // ws layout (R11-identical): 8KB packed LLC slots | 8KB packed sc0 slots.
  // No reset needed: tagged values are replay-invariant (publishes are
  // deterministic, stale==fresh for matching tags), and 0xAA poison never
  // matches tags 2..16.
  ull* sLLC; ull* sL2; int mode; int grid;
  if (d_ws != nullptr && ws_size >= 4 * HID * sizeof(ull)) {
    sLLC = (ull*)d_ws;
    sL2  = sLLC + 2 * HID;
    mode = 1;
    grid = NWORK * 8;   // workers = blockIdx%8==0 -> one XCD (speed heuristic)
  } else {
    // Out-tail fallback: LLC-only (no sc0 dirty lines over out). Rank-15
    // reads all slots strictly before overwriting this region.
    sLLC = (ull*)(out + (size_t)out_size) - 2 * HID;
    sL2  = sLLC;
    mode = 0;
    grid = NWORK;
  }

  lstm_seq_kernel<<<dim3(grid), dim3(NTHR), 0, stream>>>(
      Whh, bih, bhh, Wo, bo, out, sLLC, sL2, mode);
}

// Round 14
// 26.485 us; speedup vs baseline: 1.9698x; 1.1130x over previous
//
#include <hip/hip_runtime.h>

// Encoder is dead; LSTM input is constant zero => batch dim uniform. Real
// work: one 512-wide LSTM, 16 serial steps, broadcast 16x4 scalars to
// (16,1024,4). R13 skeleton (proven 29.5us best): 32 workers at
// blockIdx%8==0, lane-owns-slot PACKED tagged exchange (tag<<32|float),
// sequential sc0->LLC poll, sc0+agent publish, one barrier/step, h1-local
// prologue, hw exp2/rcp activations, coalesced LDS weight staging.
// This revision (single isolated change): PARALLEL 64-LANE REDUCER.
// R13's reducer had 16 lanes doing 32 LDS reads + 30 serial adds before
// publish. Now all 64 lanes of wave 0 sum their own gate-row (8 reads +
// 7 adds + row bias), 3 shfl_xor(16/32/48) deliver f/g/o sums to the
// k-owner lanes 0-15, which run activations + publish. ~200cy off the
// serial publish path per step. Summation order unchanged -> absmax 0.0.

#define NTHR   512
#define HID    512
#define TSTEPS 16
#define KPB    16      // k's per worker block
#define OUTB   16      // ranks that write output rows
#define NWORK  32
#define SW     516     // LDS weight row stride in floats (2064B: 16B-aligned)

typedef unsigned long long ull;

#define LOG2E  1.44269504f

__device__ __forceinline__ float fexp2(float x) { return __builtin_amdgcn_exp2f(x); }
__device__ __forceinline__ float frcp(float x)  { return __builtin_amdgcn_rcpf(x); }
// sigm(x)=1/(1+e^-x): x->-inf => rcp(inf)=0; x->+inf => 1. Correct saturation.
__device__ __forceinline__ float sigm(float x)  { return frcp(1.0f + fexp2(-LOG2E * x)); }
// tanh(x)=1-2/(e^{2x}+1): x->+inf => 1; x->-inf => -1. Correct saturation.
__device__ __forceinline__ float tanh_f(float x) {
  const float e = fexp2(2.0f * LOG2E * x);
  return 1.0f - 2.0f * frcp(e + 1.0f);
}

// Single sc0 probe: L1-bypass, serviced from this XCD's L2 (fast when the
// line is local; correctness never depends on it).
__device__ __forceinline__ ull probe_l2(const ull* p) {
  ull v;
  asm volatile("global_load_dwordx2 %0, %1, off sc0\n\ts_waitcnt vmcnt(0)"
               : "=v"(v) : "v"(p) : "memory");
  return v;
}

// Sequential dual poll: one sc0 probe, then one agent/LLC probe.
__device__ __forceinline__ float poll_h(const ull* sL2, const ull* sLLC,
                                        int idx, unsigned tag, bool fast) {
  ull v;
  if (fast) {
    for (;;) {
      v = probe_l2(sL2 + idx);                 // fast leg
      if ((unsigned)(v >> 32) == tag) break;
      v = __hip_atomic_load(sLLC + idx, __ATOMIC_RELAXED,
                            __HIP_MEMORY_SCOPE_AGENT);   // correctness leg
      if ((unsigned)(v >> 32) == tag) break;
    }
  } else {
    do {
      v = __hip_atomic_load(sLLC + idx, __ATOMIC_RELAXED,
                            __HIP_MEMORY_SCOPE_AGENT);
    } while ((unsigned)(v >> 32) != tag);
  }
  return __uint_as_float((unsigned)v);
}

__device__ __forceinline__ void publish(ull* sL2, ull* sLLC, int idx, ull pk,
                                        bool fast) {
  if (fast) {
    asm volatile("global_store_dwordx2 %0, %1, off sc0"
                 :: "v"(sL2 + idx), "v"(pk) : "memory");
  }
  __hip_atomic_store(sLLC + idx, pk, __ATOMIC_RELAXED, __HIP_MEMORY_SCOPE_AGENT);
}

__global__ __launch_bounds__(NTHR, 2) void lstm_seq_kernel(
    const float* __restrict__ Whh,
    const float* __restrict__ bih,
    const float* __restrict__ bhh,
    const float* __restrict__ Wo,
    const float* __restrict__ bo,
    float* __restrict__ out,
    ull* sLLC,              // [2][512] device-coherent tagged slots (packed)
    ull* sL2,               // [2][512] XCD-L2 tagged slots (sc0 ops)
    int mode)               // 1 = colocated roster + L2 fast leg, 0 = LLC only
{
  // ---- roster: mode 1 -> workers are blockIdx%8==0 (one XCD heuristic) ----
  int r;
  if (mode) {
    if (blockIdx.x & 7) return;       // non-worker: pure dispatch cost
    r = (int)(blockIdx.x >> 3);
  } else {
    r = (int)blockIdx.x;
  }
  if (r >= NWORK) return;
  const bool fast = (mode != 0);

  const int tid = threadIdx.x;
  const int w  = tid >> 6;           // wave id = h column chunk (64 cols)
  const int l  = tid & 63;           // lane = block-local gate-row
  // block-local gate-row l: gate g = l>>4, unit kk = l&15; global row
  // grow = g*HID + r*KPB + kk. Note region-row (g*16+kk) == l exactly.
  const int grow = (l >> 4) * HID + r * KPB + (l & 15);

  __shared__ float ldsw[64 * SW];               // 132KB weight staging
  __shared__ __align__(16) float chbuf[8][64];  // per-wave h chunk (exclusive)
  __shared__ float gpT[2][8][64];    // partials, parity-double-buffered
  __shared__ float hstash[HID];      // h_{r+1} for this block's output row
  __shared__ float vals[4];

  // ---- phase 1: coalesced global -> LDS weight staging ----
  // Block's weights = 4 contiguous 32KB regions (16 rows x 512 cols each).
#pragma unroll
  for (int g4 = 0; g4 < 4; ++g4) {
    const float* base = Whh + ((size_t)g4 * HID + (size_t)r * KPB) * HID;
#pragma unroll
    for (int it = 0; it < 4; ++it) {
      const int flat = it * 2048 + tid * 4;     // float index in region
      const float4 v = *reinterpret_cast<const float4*>(base + flat);
      const int rw = flat >> 9;                 // row within region (0..15)
      const int cl = flat & 511;
      *reinterpret_cast<float4*>(&ldsw[(g4 * 16 + rw) * SW + cl]) = v;
    }
  }

  // ---- h1 = f(bias) locally for THIS thread's h column (k = tid):
  // h0 == 0 kills the recurrent term; overlaps the staging loads above.
  {
    const float gi = bih[tid]           + bhh[tid];
    const float gf = bih[HID + tid]     + bhh[HID + tid];
    const float gg = bih[2*HID + tid]   + bhh[2*HID + tid];
    const float go = bih[3*HID + tid]   + bhh[3*HID + tid];
    const float c1 = sigm(gf) * 0.0f + sigm(gi) * tanh_f(gg);
    const float h1 = sigm(go) * tanh_f(c1);
    chbuf[w][l] = h1;                // wave-private: no barrier needed
    if (r == 0) hstash[tid] = h1;    // out row 0 uses h1
  }

  // ---- wave-0 lanes: per-gate-row bias; owner lanes (tid<16): c1 ----
  float c_state = 0.0f;
  float bias_row = 0.0f;
  if (w == 0) bias_row = bih[grow] + bhh[grow];   // row l's bias sum
  if (tid < KPB) {
    const int k = r * KPB + tid;
    const float bs_i = bih[k]           + bhh[k];
    const float bs_f = bih[HID + k]     + bhh[HID + k];
    const float bs_g = bih[2*HID + k]   + bhh[2*HID + k];
    c_state = sigm(bs_f) * 0.0f + sigm(bs_i) * tanh_f(bs_g);
  }

  __syncthreads();   // staging complete

  // ---- phase 2: LDS -> registers (row l, cols [64w, 64w+64)) ----
  float4 wreg[16];
#pragma unroll
  for (int j = 0; j < 16; ++j)
    wreg[j] = *reinterpret_cast<const float4*>(&ldsw[l * SW + w * 64 + j * 4]);

  // ---- steps 2..16: matvec(h_{s-1}) -> reduce -> publish h_s -> stage ----
  for (int s = 2; s <= TSTEPS; ++s) {
    const int p = s & 1;

    float4 a = make_float4(0.f, 0.f, 0.f, 0.f);
    {
      const float4* hq = reinterpret_cast<const float4*>(&chbuf[w][0]);
#pragma unroll
      for (int j = 0; j < 16; ++j) {
        const float4 h4 = hq[j];   // broadcast read: conflict-free
        a.x = fmaf(wreg[j].x, h4.x, a.x);
        a.y = fmaf(wreg[j].y, h4.y, a.y);
        a.z = fmaf(wreg[j].z, h4.z, a.z);
        a.w = fmaf(wreg[j].w, h4.w, a.w);
      }
    }
    gpT[p][w][l] = (a.x + a.y) + (a.z + a.w);
    __syncthreads();   // the only barrier per step

    // PARALLEL reducer: wave-0 lane l sums gate-row l's 8 chunk partials
    // (2-way bank aliasing = free) + row bias; shfl_xor(16/32/48) delivers
    // f/g/o sums to owner lanes 0..15, which do pointwise + publish.
    // Next step's partials go to gpT[p^1] -> no WAR with these reads.
    if (w == 0) {
      float d = gpT[p][0][l];
#pragma unroll
      for (int j = 1; j < 8; ++j) d += gpT[p][j][l];
      d += bias_row;
      const float gf = __shfl_xor(d, 16);   // lane kk <- row kk+16 (gate f)
      const float gg = __shfl_xor(d, 32);   // lane kk <- row kk+32 (gate g)
      const float go = __shfl_xor(d, 48);   // lane kk <- row kk+48 (gate o)
      if (l < KPB) {
        c_state = sigm(gf) * c_state + sigm(d) * tanh_f(gg);
        const float hv = sigm(go) * tanh_f(c_state);
        const ull pk = ((ull)(unsigned)s << 32) | (ull)__float_as_uint(hv);
        publish(sL2, sLLC, p * HID + r * KPB + l, pk, fast);
      }
    }

    // stage h_s for the next matvec (s<16); capture hstash = h_{r+1} at s==r+1
    if (s < TSTEPS) {
      const float h = poll_h(sL2, sLLC, p * HID + w * 64 + l, (unsigned)s, fast);
      if (r >= 1 && r < OUTB - 1 && s == r + 1) hstash[w * 64 + l] = h;
      chbuf[w][l] = h;   // wave-private; matvec reads of prior value are done
    }
  }

  if (r >= OUTB) return;   // ranks 16..31 only feed the recurrence

  if (r == OUTB - 1) {     // h_16 (tag 16, parity 0) never staged in-loop
    hstash[w * 64 + l] = poll_h(sL2, sLLC, w * 64 + l, (unsigned)TSTEPS, fast);
  }
  __syncthreads();

  // ---- output row t = r: 4 dot products of length 512, then broadcast ----
  if (tid < 256) {
    const int wo = tid >> 6;  // output dim 0..3 (one wave each)
    const int ll = tid & 63;
    float sacc = 0.0f;
#pragma unroll
    for (int j = 0; j < 8; ++j) {
      const int k2 = ll + 64 * j;
      sacc = fmaf(Wo[wo * HID + k2], hstash[k2], sacc);
    }
#pragma unroll
    for (int m = 32; m > 0; m >>= 1) sacc += __shfl_xor(sacc, m);
    if (ll == 0) vals[wo] = sacc + bo[wo];
  }
  __syncthreads();

  const float4 vv = make_float4(vals[0], vals[1], vals[2], vals[3]);
  float4* out4 = reinterpret_cast<float4*>(out) + (size_t)r * 1024;
  out4[tid]       = vv;   // row t=r : 1024 batch rows x 4 floats
  out4[tid + 512] = vv;
}

extern "C" void kernel_launch(void* const* d_in, const int* in_sizes, int n_in,
                              void* d_out, int out_size, void* d_ws, size_t ws_size,
                              hipStream_t stream) {
  // setup_inputs() order:
  // 0 images, 1 W1, 2 b1, 3 W2, 4 b2, 5 W3, 6 b3, 7 We, 8 be,
  // 9 Wih, 10 Whh, 11 bih, 12 bhh, 13 Wg, 14 bg, 15 Wk, 16 bk,
  // 17 Wo, 18 bo, 19 Wc, 20 bc
  const float* Whh = (const float*)d_in[10];
  const float* bih = (const float*)d_in[11];
  const float* bhh = (const float*)d_in[12];
  const float* Wo  = (const float*)d_in[17];
  const float* bo  = (const float*)d_in[18];
  float* out = (float*)d_out;

  // ws layout (R13-identical): 8KB packed LLC slots | 8KB packed sc0 slots.
  // No reset needed: tagged values are replay-invariant (publishes are
  // deterministic, stale==fresh for matching tags), and 0xAA poison never
  // matches tags 2..16.
  ull* sLLC; ull* sL2; int mode; int grid;
  if (d_ws != nullptr && ws_size >= 4 * HID * sizeof(ull)) {
    sLLC = (ull*)d_ws;
    sL2  = sLLC + 2 * HID;
    mode = 1;
    grid = NWORK * 8;   // workers = blockIdx%8==0 -> one XCD (speed heuristic)
  } else {
    // Out-tail fallback: LLC-only (no sc0 dirty lines over out). Rank-15
    // reads all slots strictly before overwriting this region.
    sLLC = (ull*)(out + (size_t)out_size) - 2 * HID;
    sL2  = sLLC;
    mode = 0;
    grid = NWORK;
  }

  lstm_seq_kernel<<<dim3(grid), dim3(NTHR), 0, stream>>>(
      Whh, bih, bhh, Wo, bo, out, sLLC, sL2, mode);
}